// Round 1
// baseline (442.122 us; speedup 1.0000x reference)
//
#include <hip/hip_runtime.h>
#include <math.h>

#define NB 8
#define NL 2048
#define NH 16
#define NE 128
#define NS 256
#define XT 64
#define NXB (NS/XT)   // 4 blocks per (b,h)

// LDS plan (union, 87040 B total):
//   phase 1: Qs [64][128] f32 @0 (32768 B), Ks1 [16][257] f32 @32768 (16448 B)
//   phase 2: Pl [256][68] f32 @0 (69632 B), Ks2 [32][132] f32 @69632 (16896 B)
__global__ __launch_bounds__(256) void fsa_main(
    const float* __restrict__ q, const float* __restrict__ k,
    const int* __restrict__ iq, const int* __restrict__ ikv,
    float* __restrict__ out_ft, float* __restrict__ out_p)
{
  __shared__ __align__(16) char smem[87040];
  float* Qs  = (float*)smem;             // [64][128]
  float* Ks1 = (float*)(smem + 32768);   // [16][257]  K^T chunk (e-major, pad 257)
  float* Pl  = (float*)smem;             // [256][68]  P (y-major, pad 68)
  float* Ks2 = (float*)(smem + 69632);   // [32][132]  K rows chunk (y-major, pad 132)

  const int t  = threadIdx.x;
  const int bh = blockIdx.x / NXB;
  const int xb = blockIdx.x % NXB;
  const int b  = bh / NH;
  const int h  = bh % NH;
  const int x0 = xb * XT;

  const int tx = t >> 5;   // 0..7  -> x rows tx*8..tx*8+7 (phase 1)
  const int ty = t & 31;   // 0..31 -> y cols ty+32j       (phase 1)

  // ---- stage Q tile: [64][128], coalesced 512B rows
  {
    const int e4  = t & 31;
    const int xr0 = t >> 5;
    #pragma unroll
    for (int p = 0; p < 8; ++p) {
      const int xr = xr0 + 8*p;
      const int lq = iq[x0 + xr];
      const float4 vv = *(const float4*)(q + (size_t)((b*NL + lq)*NH + h)*NE + 4*e4);
      *(float4*)(Qs + xr*NE + 4*e4) = vv;
    }
  }

  float acc[8][8];
  #pragma unroll
  for (int i = 0; i < 8; ++i)
    #pragma unroll
    for (int j = 0; j < 8; ++j) acc[i][j] = 0.f;

  // ---- phase 1: scores[x][y] = sum_e Q[x][e] K[y][e], e-chunks of 16
  for (int ec = 0; ec < 8; ++ec) {
    __syncthreads();
    { // stage K^T chunk: thread -> (y = t/4 + 64p, 4 e's)
      const int e4 = t & 3;
      const int yb = t >> 2;
      #pragma unroll
      for (int p = 0; p < 4; ++p) {
        const int y  = yb + 64*p;
        const int lk = ikv[y];
        const float4 vv = *(const float4*)(k + (size_t)((b*NL + lk)*NH + h)*NE + ec*16 + 4*e4);
        Ks1[(4*e4+0)*257 + y] = vv.x;
        Ks1[(4*e4+1)*257 + y] = vv.y;
        Ks1[(4*e4+2)*257 + y] = vv.z;
        Ks1[(4*e4+3)*257 + y] = vv.w;
      }
    }
    __syncthreads();
    #pragma unroll
    for (int eq = 0; eq < 4; ++eq) {
      float kv[4][8];                       // K[e][y=ty+32j], conflict-free: bank=(e+ty)%32
      #pragma unroll
      for (int e = 0; e < 4; ++e)
        #pragma unroll
        for (int j = 0; j < 8; ++j)
          kv[e][j] = Ks1[(eq*4 + e)*257 + ty + 32*j];
      #pragma unroll
      for (int i = 0; i < 8; ++i) {
        const float4 q4 = *(const float4*)(Qs + (tx*8 + i)*NE + ec*16 + eq*4); // broadcast
        #pragma unroll
        for (int j = 0; j < 8; ++j) {
          acc[i][j] = fmaf(q4.x, kv[0][j], acc[i][j]);
          acc[i][j] = fmaf(q4.y, kv[1][j], acc[i][j]);
          acc[i][j] = fmaf(q4.z, kv[2][j], acc[i][j]);
          acc[i][j] = fmaf(q4.w, kv[3][j], acc[i][j]);
        }
      }
    }
  }

  // ---- softmax over y: 8 local cols + 5-step shfl_xor within 32-lane (same-tx) group
  const float scale = 0.08838834764831845f;  // 1/sqrt(128)
  #pragma unroll
  for (int i = 0; i < 8; ++i) {
    float m = -3.4e38f;
    #pragma unroll
    for (int j = 0; j < 8; ++j) { acc[i][j] *= scale; m = fmaxf(m, acc[i][j]); }
    #pragma unroll
    for (int o = 16; o >= 1; o >>= 1) m = fmaxf(m, __shfl_xor(m, o));
    float s = 0.f;
    #pragma unroll
    for (int j = 0; j < 8; ++j) { acc[i][j] = __expf(acc[i][j] - m); s += acc[i][j]; }
    #pragma unroll
    for (int o = 16; o >= 1; o >>= 1) s += __shfl_xor(s, o);
    const float inv = 1.0f / s;
    #pragma unroll
    for (int j = 0; j < 8; ++j) acc[i][j] *= inv;
  }

  __syncthreads();   // all phase-1 LDS reads done; Qs/Ks1 area becomes Pl

  // ---- write P to LDS [y][x] and to global xqk [B,H,Sq,Sk]
  {
    float* outp = out_p + ((size_t)bh*NS + x0)*NS;
    #pragma unroll
    for (int i = 0; i < 8; ++i) {
      const int x = tx*8 + i;
      #pragma unroll
      for (int j = 0; j < 8; ++j) {
        const int y = ty + 32*j;
        Pl[y*68 + x]    = acc[i][j];   // bank=(4y+8tx+i)%32: <=4-way, one-time
        outp[x*NS + y]  = acc[i][j];   // 128B contiguous per 32-lane group
      }
    }
  }

  // ---- phase 2: O[x][e] = sum_y P[x][y] K[y][e]; thread owns x={c,c+32}, e=r*16..r*16+15
  float acc2[2][16];
  #pragma unroll
  for (int n = 0; n < 2; ++n)
    #pragma unroll
    for (int m = 0; m < 16; ++m) acc2[n][m] = 0.f;

  const int c = t & 31;
  const int r = t >> 5;

  for (int yc = 0; yc < 8; ++yc) {
    __syncthreads();
    { // stage K rows chunk [32][132]
      const int e4 = t & 7;
      const int yy = t >> 3;
      const int lk = ikv[yc*32 + yy];
      const float* src = k + (size_t)((b*NL + lk)*NH + h)*NE;
      #pragma unroll
      for (int p = 0; p < 4; ++p) {
        const float4 vv = *(const float4*)(src + 4*e4 + 32*p);
        *(float4*)(Ks2 + yy*132 + 4*e4 + 32*p) = vv;
      }
    }
    __syncthreads();
    for (int yy = 0; yy < 32; ++yy) {
      const float p0 = Pl[(yc*32 + yy)*68 + c];        // bank=(4y+c)%32: free
      const float p1 = Pl[(yc*32 + yy)*68 + c + 32];
      float4 kv4[4];
      #pragma unroll
      for (int qd = 0; qd < 4; ++qd)                   // broadcast (2 addrs/wave)
        kv4[qd] = *(const float4*)(Ks2 + yy*132 + r*16 + 4*qd);
      const float* kvf = (const float*)kv4;
      #pragma unroll
      for (int m = 0; m < 16; ++m) {
        acc2[0][m] = fmaf(p0, kvf[m], acc2[0][m]);
        acc2[1][m] = fmaf(p1, kvf[m], acc2[1][m]);
      }
    }
  }

  // ---- scatter O into zeroed [B,H,E,L]: lanes run along consecutive sorted lq[x]
  {
    float* outf = out_ft + (size_t)bh*NE*NL;
    #pragma unroll
    for (int n = 0; n < 2; ++n) {
      const int x  = x0 + c + 32*n;
      const int lq = iq[x];
      #pragma unroll
      for (int m = 0; m < 16; ++m) {
        const int e = r*16 + m;
        outf[(size_t)e*NL + lq] = acc2[n][m];
      }
    }
  }
}

extern "C" void kernel_launch(void* const* d_in, const int* in_sizes, int n_in,
                              void* d_out, int out_size, void* d_ws, size_t ws_size,
                              hipStream_t stream) {
  const float* q   = (const float*)d_in[0];
  const float* k   = (const float*)d_in[1];
  // d_in[2] = v (unused by reference), d_in[3] = attn_mask (unused)
  const int* iq    = (const int*)d_in[4];
  const int* ikv   = (const int*)d_in[5];
  float* out       = (float*)d_out;

  const size_t out_ft_elems = (size_t)NB*NH*NE*NL;   // 33,554,432
  // zero the scattered output region (capture-safe)
  hipMemsetAsync(out, 0, out_ft_elems * sizeof(float), stream);

  fsa_main<<<dim3(NB*NH*NXB), dim3(256), 0, stream>>>(
      q, k, iq, ikv, out, out + out_ft_elems);
}

// Round 2
// 366.722 us; speedup vs baseline: 1.2056x; 1.2056x over previous
//
#include <hip/hip_runtime.h>
#include <math.h>

typedef __bf16 bf16_t;
typedef __attribute__((ext_vector_type(8))) __bf16 bf16x8;
typedef __attribute__((ext_vector_type(4))) float f32x4;

#define NB 8
#define NL 2048
#define NH 16
#define NE 128
#define NS 256
#define XT 64

// LDS strides (bf16 elems). 136*2=272B=17*16 (aligned, 68 words ≡ 4 mod 32: balanced b128 reads)
// 72*2=144B=9*16 (aligned, 36 words ≡ 4 mod 32: balanced b128 reads)
#define QSTR 136
#define PSTR 72

__global__ __launch_bounds__(256, 3) void fsa_gemm(
    const float* __restrict__ q, const float* __restrict__ k,
    const int* __restrict__ iq, const int* __restrict__ ikv,
    float* __restrict__ out)
{
  float* out_ft = out;
  float* out_p  = out + (size_t)NB*NH*NE*NL;

  // union LDS: phase1 Qs[64][136] @0, Ks[64][136] @17408 ; phase2 Ps[64][72] @0, Kt[128][72] @9216
  __shared__ __align__(16) char smem[34816];
  bf16_t* Qs = (bf16_t*)smem;
  bf16_t* Ks = (bf16_t*)(smem + 17408);
  bf16_t* Ps = (bf16_t*)smem;
  bf16_t* Kt = (bf16_t*)(smem + 9216);

  const int t = threadIdx.x;
  // XCD-bijective swizzle: 512 blocks = 8 XCDs * 64; 4 x-blocks of one bh land on one XCD
  const int tile = (blockIdx.x & 7) * 64 + (blockIdx.x >> 3);
  const int bh = tile >> 2, xb = tile & 3;
  const int b = bh >> 4, h = bh & 15;
  const int x0 = xb * XT;

  const int w   = t >> 6;        // wave 0..3
  const int l15 = t & 15;        // lane&15
  const int lg  = (t & 63) >> 4; // lane group 0..3

  // ---- stage Q tile -> bf16 LDS
  {
    const int e4 = t & 31, xr = t >> 5;
    #pragma unroll
    for (int p = 0; p < 8; ++p) {
      const int x  = xr + 8*p;
      const int lq = iq[x0 + x];
      const float4 v = *(const float4*)(q + ((size_t)(b*NL + lq)*NH + h)*NE + 4*e4);
      union { bf16_t h4[4]; uint2 u; } pk;
      pk.h4[0]=(bf16_t)v.x; pk.h4[1]=(bf16_t)v.y; pk.h4[2]=(bf16_t)v.z; pk.h4[3]=(bf16_t)v.w;
      *(uint2*)(Qs + x*QSTR + 4*e4) = pk.u;
    }
  }

  f32x4 acc1[16];
  #pragma unroll
  for (int i = 0; i < 16; ++i) acc1[i] = (f32x4){0.f,0.f,0.f,0.f};
  bf16x8 aQ[4];

  // ---- GEMM1: scores[x][y] = sum_e Q[x][e] K[y][e]
  #pragma unroll
  for (int c = 0; c < 4; ++c) {
    if (c > 0) __syncthreads();
    { // stage K chunk (64 y rows) -> bf16 LDS
      const int e4 = t & 31, yr = t >> 5;
      #pragma unroll
      for (int p = 0; p < 8; ++p) {
        const int y  = yr + 8*p;
        const int lk = ikv[c*64 + y];
        const float4 v = *(const float4*)(k + ((size_t)(b*NL + lk)*NH + h)*NE + 4*e4);
        union { bf16_t h4[4]; uint2 u; } pk;
        pk.h4[0]=(bf16_t)v.x; pk.h4[1]=(bf16_t)v.y; pk.h4[2]=(bf16_t)v.z; pk.h4[3]=(bf16_t)v.w;
        *(uint2*)(Ks + y*QSTR + 4*e4) = pk.u;
      }
    }
    __syncthreads();
    if (c == 0) {
      #pragma unroll
      for (int ks = 0; ks < 4; ++ks)
        aQ[ks] = *(const bf16x8*)(Qs + (w*16 + l15)*QSTR + ks*32 + lg*8);
    }
    #pragma unroll
    for (int ks = 0; ks < 4; ++ks) {
      #pragma unroll
      for (int yt = 0; yt < 4; ++yt) {
        const bf16x8 bk = *(const bf16x8*)(Ks + (yt*16 + l15)*QSTR + ks*32 + lg*8);
        acc1[c*4 + yt] = __builtin_amdgcn_mfma_f32_16x16x32_bf16(aQ[ks], bk, acc1[c*4 + yt], 0, 0, 0);
      }
    }
  }

  // ---- softmax over y (rows x = x0 + w*16 + lg*4 + r ; cols y = yt*16 + l15)
  const float scale = 0.08838834764831845f; // 1/sqrt(128)
  #pragma unroll
  for (int r = 0; r < 4; ++r) {
    float m = -3.4e38f;
    #pragma unroll
    for (int yt = 0; yt < 16; ++yt) { acc1[yt][r] *= scale; m = fmaxf(m, acc1[yt][r]); }
    m = fmaxf(m, __shfl_xor(m, 1)); m = fmaxf(m, __shfl_xor(m, 2));
    m = fmaxf(m, __shfl_xor(m, 4)); m = fmaxf(m, __shfl_xor(m, 8));
    float s = 0.f;
    #pragma unroll
    for (int yt = 0; yt < 16; ++yt) { const float e = __expf(acc1[yt][r] - m); acc1[yt][r] = e; s += e; }
    s += __shfl_xor(s, 1); s += __shfl_xor(s, 2); s += __shfl_xor(s, 4); s += __shfl_xor(s, 8);
    const float inv = 1.0f / s;
    #pragma unroll
    for (int yt = 0; yt < 16; ++yt) acc1[yt][r] *= inv;
  }

  // ---- write P (fp32) to xqk [B,H,Sq,Sk]
  {
    float* po = out_p + ((size_t)bh*NS + x0 + w*16 + lg*4)*NS + l15;
    #pragma unroll
    for (int r = 0; r < 4; ++r)
      #pragma unroll
      for (int yt = 0; yt < 16; ++yt)
        po[(size_t)r*NS + yt*16] = acc1[yt][r];
  }

  // ---- GEMM2: O[e][x] = sum_y K[y][e] P[x][y]  (A = K^T, B = P^T via LDS)
  f32x4 acc2[2][4];
  #pragma unroll
  for (int et = 0; et < 2; ++et)
    #pragma unroll
    for (int xt = 0; xt < 4; ++xt) acc2[et][xt] = (f32x4){0.f,0.f,0.f,0.f};

  #pragma unroll
  for (int c = 0; c < 4; ++c) {
    __syncthreads();
    { // P chunk -> LDS bf16 [x][ylocal]
      const int xr = w*16 + lg*4;
      #pragma unroll
      for (int r = 0; r < 4; ++r)
        #pragma unroll
        for (int yt = 0; yt < 4; ++yt)
          Ps[(xr + r)*PSTR + yt*16 + l15] = (bf16_t)acc1[c*4 + yt][r];
    }
    { // K^T chunk -> LDS bf16 [e][ylocal], packed pair writes
      const int e4 = t & 31, yb = t >> 5;
      #pragma unroll
      for (int p = 0; p < 4; ++p) {
        const int y0  = 2*(yb + 8*p);
        const int lk0 = ikv[c*64 + y0];
        const int lk1 = ikv[c*64 + y0 + 1];
        const float4 va = *(const float4*)(k + ((size_t)(b*NL + lk0)*NH + h)*NE + 4*e4);
        const float4 vb = *(const float4*)(k + ((size_t)(b*NL + lk1)*NH + h)*NE + 4*e4);
        union { bf16_t h2[2]; unsigned u; } pr;
        pr.h2[0]=(bf16_t)va.x; pr.h2[1]=(bf16_t)vb.x; *(unsigned*)(Kt + (4*e4+0)*PSTR + y0) = pr.u;
        pr.h2[0]=(bf16_t)va.y; pr.h2[1]=(bf16_t)vb.y; *(unsigned*)(Kt + (4*e4+1)*PSTR + y0) = pr.u;
        pr.h2[0]=(bf16_t)va.z; pr.h2[1]=(bf16_t)vb.z; *(unsigned*)(Kt + (4*e4+2)*PSTR + y0) = pr.u;
        pr.h2[0]=(bf16_t)va.w; pr.h2[1]=(bf16_t)vb.w; *(unsigned*)(Kt + (4*e4+3)*PSTR + y0) = pr.u;
      }
    }
    __syncthreads();
    #pragma unroll
    for (int ks = 0; ks < 2; ++ks) {
      const bf16x8 aK0 = *(const bf16x8*)(Kt + (w*32 +  0 + l15)*PSTR + ks*32 + lg*8);
      const bf16x8 aK1 = *(const bf16x8*)(Kt + (w*32 + 16 + l15)*PSTR + ks*32 + lg*8);
      #pragma unroll
      for (int xt = 0; xt < 4; ++xt) {
        const bf16x8 bp = *(const bf16x8*)(Ps + (xt*16 + l15)*PSTR + ks*32 + lg*8);
        acc2[0][xt] = __builtin_amdgcn_mfma_f32_16x16x32_bf16(aK0, bp, acc2[0][xt], 0, 0, 0);
        acc2[1][xt] = __builtin_amdgcn_mfma_f32_16x16x32_bf16(aK1, bp, acc2[1][xt], 0, 0, 0);
      }
    }
  }

  // ---- write compact O[e][x] into out_ft[b,h,e, x] (first NS cols of each row), coalesced
  #pragma unroll
  for (int et = 0; et < 2; ++et)
    #pragma unroll
    for (int xt = 0; xt < 4; ++xt)
      #pragma unroll
      for (int r = 0; r < 4; ++r) {
        const int e = w*32 + et*16 + lg*4 + r;
        out_ft[((size_t)bh*NE + e)*NL + x0 + xt*16 + l15] = acc2[et][xt][r];
      }
}

// expand compact rows to full [E][L]: zeros except l=iq[x] -> O[e][x]
__global__ __launch_bounds__(256) void fsa_expand(
    const int* __restrict__ iq, float* __restrict__ out_ft)
{
  __shared__ int   inv[NL];
  __shared__ float oc[8][NS];
  const int t  = threadIdx.x;
  const int bh = blockIdx.x >> 4;
  const int eg = blockIdx.x & 15;

  {
    const int4 mi = {-1,-1,-1,-1};
    *(int4*)(inv + 8*t)     = mi;
    *(int4*)(inv + 8*t + 4) = mi;
  }
  __syncthreads();
  inv[iq[t]] = t;
  { // stage compact O slice [8][256]
    const int row = t >> 5, c0 = (t & 31) * 8;
    const float* src = out_ft + ((size_t)bh*NE + eg*8 + row)*NL;
    *(float4*)&oc[row][c0]     = *(const float4*)(src + c0);
    *(float4*)&oc[row][c0 + 4] = *(const float4*)(src + c0 + 4);
  }
  __syncthreads();

  #pragma unroll
  for (int r = 0; r < 8; ++r) {
    float* dst = out_ft + ((size_t)bh*NE + eg*8 + r)*NL;
    #pragma unroll
    for (int sg = 0; sg < 2; ++sg) {
      const int l = 8*t + 4*sg;
      float4 v;
      { const int i0 = inv[l+0]; v.x = (i0 >= 0) ? oc[r][i0] : 0.f; }
      { const int i1 = inv[l+1]; v.y = (i1 >= 0) ? oc[r][i1] : 0.f; }
      { const int i2 = inv[l+2]; v.z = (i2 >= 0) ? oc[r][i2] : 0.f; }
      { const int i3 = inv[l+3]; v.w = (i3 >= 0) ? oc[r][i3] : 0.f; }
      *(float4*)(dst + l) = v;
    }
  }
}

extern "C" void kernel_launch(void* const* d_in, const int* in_sizes, int n_in,
                              void* d_out, int out_size, void* d_ws, size_t ws_size,
                              hipStream_t stream) {
  const float* q = (const float*)d_in[0];
  const float* k = (const float*)d_in[1];
  // d_in[2]=v (unused by reference), d_in[3]=attn_mask (unused)
  const int* iq  = (const int*)d_in[4];
  const int* ikv = (const int*)d_in[5];
  float* out = (float*)d_out;

  fsa_gemm<<<dim3(NB*NH*(NS/XT)), dim3(256), 0, stream>>>(q, k, iq, ikv, out);
  fsa_expand<<<dim3(NB*NH*16), dim3(256), 0, stream>>>(iq, out);
}

// Round 8
// 358.672 us; speedup vs baseline: 1.2327x; 1.0224x over previous
//
#include <hip/hip_runtime.h>
#include <math.h>

typedef __bf16 bf16_t;
typedef __attribute__((ext_vector_type(8))) __bf16 bf16x8;
typedef __attribute__((ext_vector_type(4))) float f32x4;

#define NB 8
#define NL 2048
#define NH 16
#define NE 128
#define NS 256
#define XT 64

// LDS strides (bf16 elems). 136*2=272B (68 words ≡ 4 mod 32: balanced b128 reads)
// 72*2=144B (36 words ≡ 4 mod 32)
#define QSTR 136
#define PSTR 72

__global__ __launch_bounds__(256, 3) void fsa_gemm(
    const float* __restrict__ q, const float* __restrict__ k,
    const int* __restrict__ iq, const int* __restrict__ ikv,
    float* __restrict__ out)
{
  float* out_ft = out;
  float* out_p  = out + (size_t)NB*NH*NE*NL;

  // union LDS: phase1 Qs[64][136] @0, Ks[64][136] @17408 ; phase2 Ps[64][72] @0, Kt[128][72] @9216
  __shared__ __align__(16) char smem[34816];
  bf16_t* Qs = (bf16_t*)smem;
  bf16_t* Ks = (bf16_t*)(smem + 17408);
  bf16_t* Ps = (bf16_t*)smem;
  bf16_t* Kt = (bf16_t*)(smem + 9216);

  const int t = threadIdx.x;
  // XCD-bijective swizzle: 512 blocks = 8 XCDs * 64; 4 x-blocks of one bh land on one XCD
  const int tile = (blockIdx.x & 7) * 64 + (blockIdx.x >> 3);
  const int bh = tile >> 2, xb = tile & 3;
  const int b = bh >> 4, h = bh & 15;
  const int x0 = xb * XT;

  const int w   = t >> 6;        // wave 0..3
  const int l15 = t & 15;        // lane&15
  const int lg  = (t & 63) >> 4; // lane group 0..3

  // ---- stage Q tile -> bf16 LDS
  {
    const int e4 = t & 31, xr = t >> 5;
    #pragma unroll
    for (int p = 0; p < 8; ++p) {
      const int x  = xr + 8*p;
      const int lq = iq[x0 + x];
      const float4 v = *(const float4*)(q + ((size_t)(b*NL + lq)*NH + h)*NE + 4*e4);
      union { bf16_t h4[4]; uint2 u; } pk;
      pk.h4[0]=(bf16_t)v.x; pk.h4[1]=(bf16_t)v.y; pk.h4[2]=(bf16_t)v.z; pk.h4[3]=(bf16_t)v.w;
      *(uint2*)(Qs + x*QSTR + 4*e4) = pk.u;
    }
  }

  f32x4 acc1[16];
  #pragma unroll
  for (int i = 0; i < 16; ++i) acc1[i] = (f32x4){0.f,0.f,0.f,0.f};
  bf16x8 aQ[4];

  // ---- GEMM1: scores[x][y] = sum_e Q[x][e] K[y][e]
  #pragma unroll
  for (int c = 0; c < 4; ++c) {
    if (c > 0) __syncthreads();
    { // stage K chunk (64 y rows) -> bf16 LDS
      const int e4 = t & 31, yr = t >> 5;
      #pragma unroll
      for (int p = 0; p < 8; ++p) {
        const int y  = yr + 8*p;
        const int lk = ikv[c*64 + y];
        const float4 v = *(const float4*)(k + ((size_t)(b*NL + lk)*NH + h)*NE + 4*e4);
        union { bf16_t h4[4]; uint2 u; } pk;
        pk.h4[0]=(bf16_t)v.x; pk.h4[1]=(bf16_t)v.y; pk.h4[2]=(bf16_t)v.z; pk.h4[3]=(bf16_t)v.w;
        *(uint2*)(Ks + y*QSTR + 4*e4) = pk.u;
      }
    }
    __syncthreads();
    if (c == 0) {
      #pragma unroll
      for (int ks = 0; ks < 4; ++ks)
        aQ[ks] = *(const bf16x8*)(Qs + (w*16 + l15)*QSTR + ks*32 + lg*8);
    }
    #pragma unroll
    for (int ks = 0; ks < 4; ++ks) {
      #pragma unroll
      for (int yt = 0; yt < 4; ++yt) {
        const bf16x8 bk = *(const bf16x8*)(Ks + (yt*16 + l15)*QSTR + ks*32 + lg*8);
        acc1[c*4 + yt] = __builtin_amdgcn_mfma_f32_16x16x32_bf16(aQ[ks], bk, acc1[c*4 + yt], 0, 0, 0);
      }
    }
  }

  // ---- softmax over y (rows x = x0 + w*16 + lg*4 + r ; cols y = yt*16 + l15)
  const float scale = 0.08838834764831845f; // 1/sqrt(128)
  #pragma unroll
  for (int r = 0; r < 4; ++r) {
    float m = -3.4e38f;
    #pragma unroll
    for (int yt = 0; yt < 16; ++yt) { acc1[yt][r] *= scale; m = fmaxf(m, acc1[yt][r]); }
    m = fmaxf(m, __shfl_xor(m, 1)); m = fmaxf(m, __shfl_xor(m, 2));
    m = fmaxf(m, __shfl_xor(m, 4)); m = fmaxf(m, __shfl_xor(m, 8));
    float s = 0.f;
    #pragma unroll
    for (int yt = 0; yt < 16; ++yt) { const float e = __expf(acc1[yt][r] - m); acc1[yt][r] = e; s += e; }
    s += __shfl_xor(s, 1); s += __shfl_xor(s, 2); s += __shfl_xor(s, 4); s += __shfl_xor(s, 8);
    const float inv = 1.0f / s;
    #pragma unroll
    for (int yt = 0; yt < 16; ++yt) acc1[yt][r] *= inv;
  }

  // ---- write P (fp32) to xqk [B,H,Sq,Sk]
  {
    float* po = out_p + ((size_t)bh*NS + x0 + w*16 + lg*4)*NS + l15;
    #pragma unroll
    for (int r = 0; r < 4; ++r)
      #pragma unroll
      for (int yt = 0; yt < 16; ++yt)
        po[(size_t)r*NS + yt*16] = acc1[yt][r];
  }

  // ---- GEMM2: O[e][x] = sum_y K[y][e] P[x][y]  (A = K^T staged e-major with octet XOR swizzle)
  f32x4 acc2[2][4];
  #pragma unroll
  for (int et = 0; et < 2; ++et)
    #pragma unroll
    for (int xt = 0; xt < 4; ++xt) acc2[et][xt] = (f32x4){0.f,0.f,0.f,0.f};

  #pragma unroll
  for (int c = 0; c < 4; ++c) {
    __syncthreads();
    { // P chunk -> LDS bf16 [x][ylocal]
      const int xr = w*16 + lg*4;
      #pragma unroll
      for (int r = 0; r < 4; ++r)
        #pragma unroll
        for (int yt = 0; yt < 4; ++yt)
          Ps[(xr + r)*PSTR + yt*16 + l15] = (bf16_t)acc1[c*4 + yt][r];
    }
    { // K^T chunk -> LDS bf16 [e][y ^ ((e>>2&7)<<3)]  (swizzle: 16-way -> ~4-way write conflicts)
      const int e4 = t & 31, yb = t >> 5;
      const int swz = (e4 & 7) << 3;
      #pragma unroll
      for (int p = 0; p < 4; ++p) {
        const int y0  = 2*(yb + 8*p);
        const int ys  = y0 ^ swz;            // bit0 untouched: pair stays contiguous
        const int lk0 = ikv[c*64 + y0];
        const int lk1 = ikv[c*64 + y0 + 1];
        const float4 va = *(const float4*)(k + ((size_t)(b*NL + lk0)*NH + h)*NE + 4*e4);
        const float4 vb = *(const float4*)(k + ((size_t)(b*NL + lk1)*NH + h)*NE + 4*e4);
        union { bf16_t h2[2]; unsigned u; } pr;
        pr.h2[0]=(bf16_t)va.x; pr.h2[1]=(bf16_t)vb.x; *(unsigned*)(Kt + (4*e4+0)*PSTR + ys) = pr.u;
        pr.h2[0]=(bf16_t)va.y; pr.h2[1]=(bf16_t)vb.y; *(unsigned*)(Kt + (4*e4+1)*PSTR + ys) = pr.u;
        pr.h2[0]=(bf16_t)va.z; pr.h2[1]=(bf16_t)vb.z; *(unsigned*)(Kt + (4*e4+2)*PSTR + ys) = pr.u;
        pr.h2[0]=(bf16_t)va.w; pr.h2[1]=(bf16_t)vb.w; *(unsigned*)(Kt + (4*e4+3)*PSTR + ys) = pr.u;
      }
    }
    __syncthreads();
    #pragma unroll
    for (int ks = 0; ks < 2; ++ks) {
      const int er0 = w*32 + l15, er1 = w*32 + 16 + l15;
      const int sw0 = ((er0 >> 2) & 7) << 3;
      const int sw1 = ((er1 >> 2) & 7) << 3;
      const bf16x8 aK0 = *(const bf16x8*)(Kt + er0*PSTR + ((ks*32 + lg*8) ^ sw0));
      const bf16x8 aK1 = *(const bf16x8*)(Kt + er1*PSTR + ((ks*32 + lg*8) ^ sw1));
      #pragma unroll
      for (int xt = 0; xt < 4; ++xt) {
        const bf16x8 bp = *(const bf16x8*)(Ps + (xt*16 + l15)*PSTR + ks*32 + lg*8);
        acc2[0][xt] = __builtin_amdgcn_mfma_f32_16x16x32_bf16(aK0, bp, acc2[0][xt], 0, 0, 0);
        acc2[1][xt] = __builtin_amdgcn_mfma_f32_16x16x32_bf16(aK1, bp, acc2[1][xt], 0, 0, 0);
      }
    }
  }

  // ---- write compact O[e][x] into out_ft[b,h,e, x] (first NS cols of each row), coalesced
  #pragma unroll
  for (int et = 0; et < 2; ++et)
    #pragma unroll
    for (int xt = 0; xt < 4; ++xt)
      #pragma unroll
      for (int r = 0; r < 4; ++r) {
        const int e = w*32 + et*16 + lg*4 + r;
        out_ft[((size_t)bh*NE + e)*NL + x0 + xt*16 + l15] = acc2[et][xt][r];
      }
}

// expand compact rows to full [E][L]: zeros except l=iq[x] -> O[e][x]
__global__ __launch_bounds__(256) void fsa_expand(
    const int* __restrict__ iq, float* __restrict__ out_ft)
{
  __shared__ int   inv[NL];
  __shared__ float oc[16][NS];
  const int t  = threadIdx.x;
  const int bh = blockIdx.x >> 3;   // 1024 blocks: bh 0..127
  const int eg = blockIdx.x & 7;    // 8 groups x 16 e-rows

  {
    const int4 mi = {-1,-1,-1,-1};
    *(int4*)(inv + 8*t)     = mi;
    *(int4*)(inv + 8*t + 4) = mi;
  }
  __syncthreads();
  inv[iq[t]] = t;
  { // stage compact O slice [16][256]
    const int row = t >> 4, c0 = (t & 15) * 16;
    const float* src = out_ft + ((size_t)bh*NE + eg*16 + row)*NL;
    #pragma unroll
    for (int p = 0; p < 4; ++p)
      *(float4*)&oc[row][c0 + 4*p] = *(const float4*)(src + c0 + 4*p);
  }
  __syncthreads();

  #pragma unroll
  for (int r = 0; r < 16; ++r) {
    float* dst = out_ft + ((size_t)bh*NE + eg*16 + r)*NL;
    #pragma unroll
    for (int half = 0; half < 2; ++half) {
      const int l = half*1024 + 4*t;   // dense: 256 lanes x 16B contiguous
      f32x4 v;
      { const int i0 = inv[l+0]; v.x = (i0 >= 0) ? oc[r][i0] : 0.f; }
      { const int i1 = inv[l+1]; v.y = (i1 >= 0) ? oc[r][i1] : 0.f; }
      { const int i2 = inv[l+2]; v.z = (i2 >= 0) ? oc[r][i2] : 0.f; }
      { const int i3 = inv[l+3]; v.w = (i3 >= 0) ? oc[r][i3] : 0.f; }
      __builtin_nontemporal_store(v, (f32x4*)(dst + l));
    }
  }
}

extern "C" void kernel_launch(void* const* d_in, const int* in_sizes, int n_in,
                              void* d_out, int out_size, void* d_ws, size_t ws_size,
                              hipStream_t stream) {
  const float* q = (const float*)d_in[0];
  const float* k = (const float*)d_in[1];
  // d_in[2]=v (unused by reference), d_in[3]=attn_mask (unused)
  const int* iq  = (const int*)d_in[4];
  const int* ikv = (const int*)d_in[5];
  float* out = (float*)d_out;

  fsa_gemm<<<dim3(NB*NH*(NS/XT)), dim3(256), 0, stream>>>(q, k, iq, ikv, out);
  fsa_expand<<<dim3(NB*NH*8), dim3(256), 0, stream>>>(iq, out);
}